// Round 1
// baseline (4200.773 us; speedup 1.0000x reference)
//
#include <hip/hip_runtime.h>

#define DIM 128
#define NAGENT 100
#define NCITY 5000
#define NBATCH 64

// ---------------------------------------------------------------------------
// Kernel 1: k[b][a][e] = sum_d agent[b][a][d] * Wk[d][e]   (fp64 accumulate)
// one block per (b,a), 128 threads (thread = output dim e)
// ---------------------------------------------------------------------------
__global__ void proj_k_kernel(const float* __restrict__ agent,
                              const float* __restrict__ Wk,
                              double* __restrict__ kproj) {
    const int ba = blockIdx.x;          // 0 .. NBATCH*NAGENT-1
    const int e  = threadIdx.x;         // 0 .. 127

    __shared__ float s_a[DIM];
    s_a[e] = agent[(size_t)ba * DIM + e];
    __syncthreads();

    double acc = 0.0;
    #pragma unroll 8
    for (int d = 0; d < DIM; ++d) {
        acc += (double)s_a[d] * (double)Wk[d * DIM + e];  // coalesced over e
    }
    kproj[(size_t)ba * DIM + e] = acc;
}

// ---------------------------------------------------------------------------
// Kernel 2: per (b,c): q = city_row * Wq (fp64); scores_a = q . k[b][a];
//           out[b][c] = argmax_a scores_a   (first-index tie-break, numpy)
// one block per (b,c), 128 threads
// ---------------------------------------------------------------------------
__global__ void score_argmax_kernel(const float* __restrict__ city,
                                    const float* __restrict__ Wq,
                                    const double* __restrict__ kproj,
                                    int* __restrict__ out) {
    const int bc = blockIdx.x;          // 0 .. NBATCH*NCITY-1
    const int b  = bc / NCITY;
    const int e  = threadIdx.x;         // 0 .. 127

    __shared__ float  s_c[DIM];
    __shared__ double s_q[DIM];
    __shared__ double s_best[DIM];
    __shared__ int    s_bidx[DIM];

    s_c[e] = city[(size_t)bc * DIM + e];
    __syncthreads();

    // q_e = sum_d city[d] * Wq[d][e]  -- Wq read coalesced across e
    double acc = 0.0;
    #pragma unroll 8
    for (int d = 0; d < DIM; ++d) {
        acc += (double)s_c[d] * (double)Wq[d * DIM + e];
    }
    s_q[e] = acc;
    __syncthreads();

    // each of the first NAGENT threads computes one score
    double best = -1.0e300;
    int    bidx = 0x7fffffff;
    if (e < NAGENT) {
        const double* krow = kproj + ((size_t)b * NAGENT + e) * DIM;
        double sc = 0.0;
        #pragma unroll 8
        for (int d = 0; d < DIM; ++d) {
            sc += s_q[d] * krow[d];
        }
        best = sc;
        bidx = e;
    }
    s_best[e] = best;
    s_bidx[e] = bidx;
    __syncthreads();

    // tree argmax, first-index tie-break (match np.argmax semantics)
    for (int off = 64; off > 0; off >>= 1) {
        if (e < off) {
            double ov = s_best[e + off];
            int    oi = s_bidx[e + off];
            if (ov > s_best[e] || (ov == s_best[e] && oi < s_bidx[e])) {
                s_best[e] = ov;
                s_bidx[e] = oi;
            }
        }
        __syncthreads();
    }

    if (e == 0) out[bc] = s_bidx[0];
}

// ---------------------------------------------------------------------------
extern "C" void kernel_launch(void* const* d_in, const int* in_sizes, int n_in,
                              void* d_out, int out_size, void* d_ws, size_t ws_size,
                              hipStream_t stream) {
    const float* agent = (const float*)d_in[0];   // [B, NA, D]
    const float* city  = (const float*)d_in[1];   // [B, NC, D]
    const float* Wq    = (const float*)d_in[2];   // [D, D]
    const float* Wk    = (const float*)d_in[3];   // [D, D]
    int* out = (int*)d_out;                       // [B, NC]

    double* kproj = (double*)d_ws;                // [B, NA, D] fp64 (6.55 MB)

    proj_k_kernel<<<NBATCH * NAGENT, DIM, 0, stream>>>(agent, Wk, kproj);
    score_argmax_kernel<<<NBATCH * NCITY, DIM, 0, stream>>>(city, Wq, kproj, out);
}

// Round 2
// 323.834 us; speedup vs baseline: 12.9720x; 12.9720x over previous
//
#include <hip/hip_runtime.h>

#define DIM     128
#define NAGENT  100
#define NCITY   5000
#define NBATCH  64
#define NA_PAD  101          // LDS stride (fp32) for transposed kproj in gmat kernel
#define SUSP_CAP 16384
#define EPS     1e-3f
#define CTILES  ((NCITY + 255) / 256)   // 20

// ---- workspace layout (bytes) ----
// [0,4)            suspect counter (int)
// [512, 512+64K)   suspect list (int bc indices)
// [66048, +6.55MB) kproj64  [B][NA][D] fp64
// [6619648,+3.3MB) G32      [B][NA][D] fp32  (row = agent, contiguous d)
#define OFF_CNT 0
#define OFF_SUS 512
#define OFF_KP  66048
#define OFF_G32 6619648

// ---------------------------------------------------------------------------
// K1: kproj64[b][a][e] = sum_d agent[b][a][d] * Wk[d][e]   (fp64, exact-ish)
// one block per (b,a), 128 threads (thread = e). Validated in round 1.
// ---------------------------------------------------------------------------
__global__ __launch_bounds__(128) void proj_k_kernel(const float* __restrict__ agent,
                                                     const float* __restrict__ Wk,
                                                     double* __restrict__ kp64) {
    const int ba = blockIdx.x;
    const int e  = threadIdx.x;

    __shared__ float s_a[DIM];
    s_a[e] = agent[(size_t)ba * DIM + e];
    __syncthreads();

    double acc = 0.0;
    #pragma unroll 8
    for (int d = 0; d < DIM; ++d)
        acc += (double)s_a[d] * (double)Wk[d * DIM + e];   // coalesced over e
    kp64[(size_t)ba * DIM + e] = acc;
}

// ---------------------------------------------------------------------------
// K2: G32[b][a][d] = (float) sum_e Wq[d][e] * kp64[b][a][e]   (fp64 accumulate)
// grid = NBATCH*8 blocks; block = (b, chunk of 16 d-rows), 256 threads.
// kproj staged transposed in LDS as fp32 [e][NA_PAD] (52 KB < 64 KB limit).
// ---------------------------------------------------------------------------
__global__ __launch_bounds__(256) void gmat_kernel(const float* __restrict__ Wq,
                                                   const double* __restrict__ kp64,
                                                   float* __restrict__ G32) {
    const int b      = blockIdx.x >> 3;
    const int dchunk = blockIdx.x & 7;
    const int tid    = threadIdx.x;

    __shared__ float s_kp[DIM][NA_PAD];   // [e][a], 51.7 KB

    const double* kpb = kp64 + (size_t)b * NAGENT * DIM;
    for (int i = tid; i < NAGENT * DIM; i += 256) {
        int a = i >> 7;          // i = a*128 + e
        int e = i & 127;
        s_kp[e][a] = (float)kpb[i];    // coalesced global read
    }
    __syncthreads();

    const int d0 = dchunk * 16;
    for (int i = tid; i < 16 * NAGENT; i += 256) {
        int dl = i / NAGENT;
        int a  = i - dl * NAGENT;
        int d  = d0 + dl;
        const float* wq = Wq + d * DIM;
        double acc = 0.0;
        #pragma unroll 8
        for (int e = 0; e < DIM; ++e)
            acc += (double)wq[e] * (double)s_kp[e][a];
        G32[((size_t)b * NAGENT + a) * DIM + d] = (float)acc;
    }
}

// ---------------------------------------------------------------------------
// K3 (main): per city c: score[a] = sum_d city[c][d] * G[b][a][d]  (fp32)
// thread = city (city row in 128 VGPRs), G staged in LDS, read via b128
// broadcasts. Tracks top-2; gap < EPS -> push to suspect list for fp64 fix.
// ---------------------------------------------------------------------------
__global__ __launch_bounds__(256) void score_kernel(const float* __restrict__ city,
                                                    const float* __restrict__ G32,
                                                    int* __restrict__ out,
                                                    int* __restrict__ counter,
                                                    int* __restrict__ suspects) {
    const int b   = blockIdx.x / CTILES;
    const int ct  = blockIdx.x % CTILES;
    const int tid = threadIdx.x;
    const int c   = ct * 256 + tid;

    __shared__ float s_g[NAGENT * DIM];   // 51.2 KB

    // stage G for this batch (coalesced float4)
    {
        const float4* gsrc = (const float4*)(G32 + (size_t)b * NAGENT * DIM);
        float4* gdst = (float4*)s_g;
        for (int i = tid; i < NAGENT * DIM / 4; i += 256)
            gdst[i] = gsrc[i];
    }

    float4 cv[DIM / 4];
    const int bc = b * NCITY + c;
    if (c < NCITY) {
        const float4* csrc = (const float4*)(city + (size_t)bc * DIM);
        #pragma unroll
        for (int j = 0; j < DIM / 4; ++j) cv[j] = csrc[j];
    }
    __syncthreads();
    if (c >= NCITY) return;   // no barriers after this point

    float best1 = -1e30f, best2 = -1e30f;
    int   bidx  = 0;
    for (int a = 0; a < NAGENT; ++a) {
        const float4* g4 = (const float4*)(s_g + a * DIM);
        float a0 = 0.f, a1 = 0.f, a2 = 0.f, a3 = 0.f;
        #pragma unroll
        for (int j = 0; j < DIM / 4; ++j) {
            float4 g = g4[j];             // LDS broadcast (all lanes same addr)
            a0 = fmaf(cv[j].x, g.x, a0);
            a1 = fmaf(cv[j].y, g.y, a1);
            a2 = fmaf(cv[j].z, g.z, a2);
            a3 = fmaf(cv[j].w, g.w, a3);
        }
        float sc = (a0 + a1) + (a2 + a3);
        if (sc > best1)      { best2 = best1; best1 = sc; bidx = a; }
        else if (sc > best2) { best2 = sc; }
    }
    out[bc] = bidx;
    if (best1 - best2 < EPS) {
        int slot = atomicAdd(counter, 1);
        if (slot < SUSP_CAP) suspects[slot] = bc;
    }
}

// ---------------------------------------------------------------------------
// K4: exact fp64 re-resolution of suspect rows (round-1-validated math:
// q = city*Wq in fp64, scores = q . kp64, argmax with first-index tie-break)
// ---------------------------------------------------------------------------
__global__ __launch_bounds__(128) void recheck_kernel(const float* __restrict__ city,
                                                      const float* __restrict__ Wq,
                                                      const double* __restrict__ kp64,
                                                      const int* __restrict__ counter,
                                                      const int* __restrict__ suspects,
                                                      int* __restrict__ out) {
    int n = *counter;
    if (n > SUSP_CAP) n = SUSP_CAP;
    const int e = threadIdx.x;

    __shared__ float  s_c[DIM];
    __shared__ double s_q[DIM];
    __shared__ double s_best[DIM];
    __shared__ int    s_bidx[DIM];

    for (int s = blockIdx.x; s < n; s += gridDim.x) {
        const int bc = suspects[s];
        const int b  = bc / NCITY;

        s_c[e] = city[(size_t)bc * DIM + e];
        __syncthreads();

        double acc = 0.0;
        #pragma unroll 8
        for (int d = 0; d < DIM; ++d)
            acc += (double)s_c[d] * (double)Wq[d * DIM + e];
        s_q[e] = acc;
        __syncthreads();

        double best = -1.0e300;
        int    bidx = 0x7fffffff;
        if (e < NAGENT) {
            const double* kr = kp64 + ((size_t)b * NAGENT + e) * DIM;
            double sc = 0.0;
            #pragma unroll 8
            for (int d = 0; d < DIM; ++d)
                sc += s_q[d] * kr[d];
            best = sc; bidx = e;
        }
        s_best[e] = best; s_bidx[e] = bidx;
        __syncthreads();

        for (int off = 64; off > 0; off >>= 1) {
            if (e < off) {
                double ov = s_best[e + off];
                int    oi = s_bidx[e + off];
                if (ov > s_best[e] || (ov == s_best[e] && oi < s_bidx[e])) {
                    s_best[e] = ov; s_bidx[e] = oi;
                }
            }
            __syncthreads();
        }
        if (e == 0) out[bc] = s_bidx[0];
        __syncthreads();   // protect shared reuse next iteration
    }
}

// ---------------------------------------------------------------------------
extern "C" void kernel_launch(void* const* d_in, const int* in_sizes, int n_in,
                              void* d_out, int out_size, void* d_ws, size_t ws_size,
                              hipStream_t stream) {
    const float* agent = (const float*)d_in[0];   // [B, NA, D]
    const float* city  = (const float*)d_in[1];   // [B, NC, D]
    const float* Wq    = (const float*)d_in[2];   // [D, D]
    const float* Wk    = (const float*)d_in[3];   // [D, D]
    int* out = (int*)d_out;                       // [B, NC]

    char*   ws       = (char*)d_ws;
    int*    counter  = (int*)(ws + OFF_CNT);
    int*    suspects = (int*)(ws + OFF_SUS);
    double* kp64     = (double*)(ws + OFF_KP);
    float*  G32      = (float*)(ws + OFF_G32);

    hipMemsetAsync(counter, 0, sizeof(int), stream);

    proj_k_kernel<<<NBATCH * NAGENT, DIM, 0, stream>>>(agent, Wk, kp64);
    gmat_kernel<<<NBATCH * 8, 256, 0, stream>>>(Wq, kp64, G32);
    score_kernel<<<NBATCH * CTILES, 256, 0, stream>>>(city, G32, out, counter, suspects);
    recheck_kernel<<<256, DIM, 0, stream>>>(city, Wq, kp64, counter, suspects, out);
}